// Round 16
// baseline (585.307 us; speedup 1.0000x reference)
//
#include <hip/hip_runtime.h>
#include <hip/hip_fp16.h>

#define NN 50000
#define NE 800000
#define NB 4
#define SLICE 12500         // NN/NB
#define NR2 (NN * NB)       // 200000
#define SCAN_BLOCKS ((NR2 + 1023) / 1024)  // 196

// ---------------- wave helpers ----------------
__device__ __forceinline__ float wsum64(float v) {
#pragma unroll
  for (int off = 32; off; off >>= 1) v += __shfl_xor(v, off, 64);
  return v;
}
__device__ __forceinline__ int wisum64(int v) {
#pragma unroll
  for (int off = 32; off; off >>= 1) v += __shfl_xor(v, off, 64);
  return v;
}
__device__ __forceinline__ float lrelu(float x) { return x > 0.0f ? x : 0.2f * x; }
#define RFL(v) __builtin_amdgcn_readfirstlane(v)

// 4 packed halves (8B) -> float4
__device__ __forceinline__ float4 h4tof4(uint2 raw) {
  __half2 a = *reinterpret_cast<const __half2*>(&raw.x);
  __half2 b = *reinterpret_cast<const __half2*>(&raw.y);
  float2 fa = __half22float2(a), fb = __half22float2(b);
  return make_float4(fa.x, fa.y, fb.x, fb.y);
}
// 8 packed halves (16B) -> two float4
__device__ __forceinline__ void h8tof8(uint4 raw, float4& lo, float4& hi) {
  __half2 a = *reinterpret_cast<const __half2*>(&raw.x);
  __half2 b = *reinterpret_cast<const __half2*>(&raw.y);
  __half2 c = *reinterpret_cast<const __half2*>(&raw.z);
  __half2 d = *reinterpret_cast<const __half2*>(&raw.w);
  float2 fa = __half22float2(a), fb = __half22float2(b);
  float2 fc = __half22float2(c), fd = __half22float2(d);
  lo = make_float4(fa.x, fa.y, fb.x, fb.y);
  hi = make_float4(fc.x, fc.y, fd.x, fd.y);
}

// ---------------- fp32 -> fp16 conversion (in_feat) ----------------
__global__ __launch_bounds__(256) void cvt_x_k(const float* __restrict__ in,
                                               __half* __restrict__ out, int n4) {
  int i = blockIdx.x * 256 + threadIdx.x;
  if (i >= n4) return;
  float4 v = *(const float4*)&in[i << 2];
  __half2 a = __floats2half2_rn(v.x, v.y);
  __half2 b = __floats2half2_rn(v.z, v.w);
  uint2 p;
  p.x = *reinterpret_cast<const unsigned int*>(&a);
  p.y = *reinterpret_cast<const unsigned int*>(&b);
  *(uint2*)&out[i << 2] = p;
}

// ---------------- weight block-transposes for f4 GEMV ----------------
// Wt[cc*256 + c*4 + u] = Worig[row=cc*4+u][c]
// l1: row = h*128+k (512 rows), Worig[row][c] = W1[k*256 + h*64 + c]
__global__ __launch_bounds__(256) void tr_w1_k(const float* __restrict__ W1,
                                               float* __restrict__ Wt1) {
  int o = blockIdx.x * 256 + threadIdx.x;  // 0..32767
  if (o >= 64 * 512) return;
  int cc = o >> 8, rem = o & 255, c = rem >> 2, u = rem & 3;
  int row = cc * 4 + u;
  int h = row >> 7, k = row & 127;
  Wt1[o] = W1[k * 256 + (h << 6) + c];
}
// hidden: row = h*64+k (256 rows), Worig[row][c] = Wh[l][k*256 + h*64 + c]
__global__ __launch_bounds__(256) void tr_wh_k(const float* __restrict__ Wh,
                                               float* __restrict__ Wth) {
  int o = blockIdx.x * 256 + threadIdx.x;  // 0..49151
  if (o >= 3 * 64 * 256) return;
  int l = o / 16384, oo = o & 16383;
  int cc = oo >> 8, rem = oo & 255, c = rem >> 2, u = rem & 3;
  int row = cc * 4 + u;
  int h = row >> 6, k = row & 63;
  Wth[o] = Wh[l * 16384 + k * 256 + (h << 6) + c];
}
// final: Mt[cc*256 + c*4 + u] = M[(cc*4+u)*64 + c]
__global__ __launch_bounds__(256) void tr_m_k(const float* __restrict__ M,
                                              float* __restrict__ Mt) {
  int o = blockIdx.x * 256 + threadIdx.x;  // 0..16383
  if (o >= 64 * 256) return;
  int cc = o >> 8, rem = o & 255, c = rem >> 2, u = rem & 3;
  int row = cc * 4 + u;
  Mt[o] = M[row * 64 + c];
}

// ---------------- CSR build (bucketed by src slice) ----------------
__global__ void zero_int_k(int* __restrict__ p, int n) {
  int i = blockIdx.x * 256 + threadIdx.x;
  if (i < n) p[i] = 0;
}

__global__ void count_deg2_k(const int* __restrict__ src, const int* __restrict__ dst,
                             int* __restrict__ deg2) {
  int e = blockIdx.x * 256 + threadIdx.x;
  if (e < NE) {
    int b = src[e] / SLICE;
    atomicAdd(&deg2[dst[e] * NB + b], 1);
  }
}

// (a) per-block sums
__global__ __launch_bounds__(1024) void scan_part_k(const int* __restrict__ deg2,
                                                    int* __restrict__ part) {
  __shared__ int ws[16];
  int tid = threadIdx.x, w = tid >> 6;
  int i = blockIdx.x * 1024 + tid;
  int v = (i < NR2) ? deg2[i] : 0;
  int s = wisum64(v);
  if ((tid & 63) == 0) ws[w] = s;
  __syncthreads();
  if (tid == 0) {
    int tot = 0;
#pragma unroll
    for (int u = 0; u < 16; ++u) tot += ws[u];
    part[blockIdx.x] = tot;
  }
}

// (b) scan the 196 partials (one small block)
__global__ void scan_mid_k(int* __restrict__ part, int* __restrict__ rp2) {
  __shared__ int sh[256];
  int tid = threadIdx.x;
  int v = (tid < SCAN_BLOCKS) ? part[tid] : 0;
  sh[tid] = v;
  __syncthreads();
  for (int off = 1; off < 256; off <<= 1) {
    int t = (tid >= off) ? sh[tid - off] : 0;
    __syncthreads();
    sh[tid] += t;
    __syncthreads();
  }
  int incl = sh[tid];
  if (tid < SCAN_BLOCKS) part[tid] = incl - v;  // exclusive
  if (tid == SCAN_BLOCKS - 1) rp2[NR2] = incl;  // total == NE
}

// (c) local scan + block offset -> rp2 / cur2
__global__ __launch_bounds__(1024) void scan_apply_k(const int* __restrict__ deg2,
                                                     const int* __restrict__ part,
                                                     int* __restrict__ rp2,
                                                     int* __restrict__ cur2) {
  __shared__ int ws[16];
  int tid = threadIdx.x, lane = tid & 63, w = tid >> 6;
  int i = blockIdx.x * 1024 + tid;
  int v = (i < NR2) ? deg2[i] : 0;
  int incl = v;
#pragma unroll
  for (int off = 1; off < 64; off <<= 1) {
    int t = __shfl_up(incl, off, 64);
    if (lane >= off) incl += t;
  }
  if (lane == 63) ws[w] = incl;
  __syncthreads();
  if (tid == 0) {
    int run = 0;
#pragma unroll
    for (int u = 0; u < 16; ++u) { int t = ws[u]; ws[u] = run; run += t; }
  }
  __syncthreads();
  int excl = incl - v + ws[w] + part[blockIdx.x];
  if (i < NR2) {
    rp2[i] = excl;
    cur2[i] = excl;
  }
}

__global__ void fill_csr2_k(const int* __restrict__ src, const int* __restrict__ dst,
                            int* __restrict__ cur2, int* __restrict__ csr_src) {
  int e = blockIdx.x * 256 + threadIdx.x;
  if (e < NE) {
    int sv = src[e];
    int b = sv / SLICE;
    int pos = atomicAdd(&cur2[dst[e] * NB + b], 1);
    csr_src[pos] = sv;
  }
}

// ---------------- tiny precomputes ----------------
__global__ void compute_q_k(const float* __restrict__ W, const float* __restrict__ al,
                            const float* __restrict__ ar, float* __restrict__ Q, int KDIM) {
  int idx = blockIdx.x * 256 + threadIdx.x;
  if (idx >= KDIM * 8) return;
  int k = idx >> 3, c = idx & 7;
  int h = c & 3;
  const float* av = (c < 4 ? al : ar) + h * 64;
  const float* wrow = W + (size_t)k * 256 + h * 64;
  float s = 0.0f;
  for (int m = 0; m < 64; ++m) s += wrow[m] * av[m];
  Q[idx] = s;
}

__global__ void compute_m_k(const float* __restrict__ Wh2, const float* __restrict__ Wo,
                            float* __restrict__ M) {
  int row = blockIdx.x;  // 0..255
  int d = threadIdx.x;   // 0..63
  int h = row >> 6, k = row & 63;
  float s = 0.0f;
  for (int j = 0; j < 64; ++j)
    s += Wh2[k * 256 + h * 64 + j] * Wo[(h * 64 + j) * 64 + d];
  M[row * 64 + d] = s;
}

__global__ void compute_c_k(const float* __restrict__ bh2, const float* __restrict__ Wo,
                            const float* __restrict__ bo, float* __restrict__ cvec) {
  int d = threadIdx.x;
  if (d >= 64) return;
  float s = bo[d];
  for (int m = 0; m < 256; ++m) s += bh2[m] * Wo[m * 64 + d];
  cvec[d] = s;
}

// ---------------- el/er for layer 1 (fp32 input, exact) ----------------
__global__ __launch_bounds__(256) void eler_l1_k(const float* __restrict__ X,
                                                 const float* __restrict__ Q,
                                                 float* __restrict__ elp,
                                                 float* __restrict__ erp) {
  int n = RFL(blockIdx.x * 4 + (threadIdx.x >> 6));
  int lane = threadIdx.x & 63;
  float2 xv = *(const float2*)&X[(n << 7) + (lane << 1)];
  float4 qa0 = *(const float4*)&Q[(lane * 2) * 8];
  float4 qb0 = *(const float4*)&Q[(lane * 2) * 8 + 4];
  float4 qa1 = *(const float4*)&Q[(lane * 2 + 1) * 8];
  float4 qb1 = *(const float4*)&Q[(lane * 2 + 1) * 8 + 4];
  float p[8];
  p[0] = xv.x * qa0.x + xv.y * qa1.x; p[1] = xv.x * qa0.y + xv.y * qa1.y;
  p[2] = xv.x * qa0.z + xv.y * qa1.z; p[3] = xv.x * qa0.w + xv.y * qa1.w;
  p[4] = xv.x * qb0.x + xv.y * qb1.x; p[5] = xv.x * qb0.y + xv.y * qb1.y;
  p[6] = xv.x * qb0.z + xv.y * qb1.z; p[7] = xv.x * qb0.w + xv.y * qb1.w;
#pragma unroll
  for (int c = 0; c < 8; ++c) p[c] = wsum64(p[c]);
  if (lane == 0) {
    *(float4*)&elp[n << 2] = make_float4(p[0], p[1], p[2], p[3]);
    *(float4*)&erp[n << 2] = make_float4(p[4], p[5], p[6], p[7]);
  }
}

// ---------------- bucket edge-loop body (64-dim, fp16 x) ----------------
__device__ __forceinline__ void agg_bucket64(const __half* __restrict__ x,
                                             const float* __restrict__ el,
                                             const int* __restrict__ csr,
                                             int beg, int end, int q, int r4,
                                             float erq, float4& a, float& sw) {
  int j = beg;
  for (; j + 4 <= end; j += 4) {
    int s0 = csr[j + 0], s1 = csr[j + 1], s2 = csr[j + 2], s3 = csr[j + 3];
    float e0 = el[(s0 << 2) + q], e1 = el[(s1 << 2) + q];
    float e2 = el[(s2 << 2) + q], e3 = el[(s3 << 2) + q];
    uint2 h0 = *(const uint2*)&x[(s0 << 6) + r4];
    uint2 h1 = *(const uint2*)&x[(s1 << 6) + r4];
    uint2 h2 = *(const uint2*)&x[(s2 << 6) + r4];
    uint2 h3 = *(const uint2*)&x[(s3 << 6) + r4];
    float4 x0 = h4tof4(h0);
    float4 x1 = h4tof4(h1);
    float4 x2 = h4tof4(h2);
    float4 x3 = h4tof4(h3);
    float w0 = __expf(lrelu(e0 + erq)), w1 = __expf(lrelu(e1 + erq));
    float w2 = __expf(lrelu(e2 + erq)), w3 = __expf(lrelu(e3 + erq));
    sw += w0 + w1 + w2 + w3;
    a.x = fmaf(w0, x0.x, a.x); a.y = fmaf(w0, x0.y, a.y);
    a.z = fmaf(w0, x0.z, a.z); a.w = fmaf(w0, x0.w, a.w);
    a.x = fmaf(w1, x1.x, a.x); a.y = fmaf(w1, x1.y, a.y);
    a.z = fmaf(w1, x1.z, a.z); a.w = fmaf(w1, x1.w, a.w);
    a.x = fmaf(w2, x2.x, a.x); a.y = fmaf(w2, x2.y, a.y);
    a.z = fmaf(w2, x2.z, a.z); a.w = fmaf(w2, x2.w, a.w);
    a.x = fmaf(w3, x3.x, a.x); a.y = fmaf(w3, x3.y, a.y);
    a.z = fmaf(w3, x3.z, a.z); a.w = fmaf(w3, x3.w, a.w);
  }
  for (; j < end; ++j) {
    int s0 = csr[j];
    float e0 = el[(s0 << 2) + q];
    uint2 h0 = *(const uint2*)&x[(s0 << 6) + r4];
    float4 x0 = h4tof4(h0);
    float w0 = __expf(lrelu(e0 + erq));
    sw += w0;
    a.x = fmaf(w0, x0.x, a.x); a.y = fmaf(w0, x0.y, a.y);
    a.z = fmaf(w0, x0.z, a.z); a.w = fmaf(w0, x0.w, a.w);
  }
}

// ---------------- fused hidden layer (bucketed fp16 agg + f4 GEMV) -------------
__global__ __launch_bounds__(256) void fused_hidden_k(
    const __half* __restrict__ x, const float* __restrict__ el,
    const float* __restrict__ er, const float* __restrict__ Wt,
    const float* __restrict__ b, const float* __restrict__ Qn,
    const int* __restrict__ rp2, const int* __restrict__ csr_src,
    __half* __restrict__ hout, float* __restrict__ eln, float* __restrict__ ern) {
  __shared__ float gs[4][1024];
  int wave = threadIdx.x >> 6, lane = threadIdx.x & 63;
  int q = lane >> 4, r = lane & 15, r4 = r << 2;
  int base = (blockIdx.x * 4 + wave) * 4;
  float* gw = gs[wave];
  float4 av[4];
  float swv[4], erqv[4];
#pragma unroll
  for (int t = 0; t < 4; ++t) {
    av[t] = make_float4(0.f, 0.f, 0.f, 0.f);
    swv[t] = 0.f;
    erqv[t] = er[((base + t) << 2) + q];
  }
#pragma unroll 1
  for (int bkt = 0; bkt < NB; ++bkt) {
#pragma unroll
    for (int t = 0; t < 4; ++t) {
      int nb = RFL((base + t) * NB + bkt);
      int beg = rp2[nb], end = rp2[nb + 1];
      agg_bucket64(x, el, csr_src, beg, end, q, r4, erqv[t], av[t], swv[t]);
    }
  }
#pragma unroll
  for (int t = 0; t < 4; ++t) {
    float inv = swv[t] > 0.f ? 1.0f / swv[t] : 0.f;
    *(float4*)&gw[t * 256 + (q << 6) + r4] =
        make_float4(av[t].x * inv, av[t].y * inv, av[t].z * inv, av[t].w * inv);
  }
  // f4 GEMV: wv = rows rr..rr+3 at column lane (block-transposed, coalesced)
  float y0 = 0.f, y1 = 0.f, y2 = 0.f, y3 = 0.f;
  int l4 = lane << 2;
  for (int rr = 0; rr < 256; rr += 4) {
    float4 wv = *(const float4*)&Wt[(rr << 6) + l4];  // (rr/4)*256 + lane*4
    float4 g0 = *(const float4*)&gw[0 * 256 + rr];
    float4 g1 = *(const float4*)&gw[1 * 256 + rr];
    float4 g2 = *(const float4*)&gw[2 * 256 + rr];
    float4 g3 = *(const float4*)&gw[3 * 256 + rr];
    y0 = fmaf(g0.x, wv.x, y0); y0 = fmaf(g0.y, wv.y, y0);
    y0 = fmaf(g0.z, wv.z, y0); y0 = fmaf(g0.w, wv.w, y0);
    y1 = fmaf(g1.x, wv.x, y1); y1 = fmaf(g1.y, wv.y, y1);
    y1 = fmaf(g1.z, wv.z, y1); y1 = fmaf(g1.w, wv.w, y1);
    y2 = fmaf(g2.x, wv.x, y2); y2 = fmaf(g2.y, wv.y, y2);
    y2 = fmaf(g2.z, wv.z, y2); y2 = fmaf(g2.w, wv.w, y2);
    y3 = fmaf(g3.x, wv.x, y3); y3 = fmaf(g3.y, wv.y, y3);
    y3 = fmaf(g3.z, wv.z, y3); y3 = fmaf(g3.w, wv.w, y3);
  }
  float bsum = b[lane] + b[64 + lane] + b[128 + lane] + b[192 + lane];
  float4 qa = *(const float4*)&Qn[lane * 8];
  float4 qb = *(const float4*)&Qn[lane * 8 + 4];
  float ys[4] = {y0, y1, y2, y3};
#pragma unroll
  for (int t = 0; t < 4; ++t) {
    int n = base + t;
    float yv = 0.25f * (ys[t] + bsum);
    hout[(n << 6) + lane] = __float2half(yv);
    float e0 = wsum64(yv * qa.x), e1 = wsum64(yv * qa.y);
    float e2 = wsum64(yv * qa.z), e3 = wsum64(yv * qa.w);
    float r0 = wsum64(yv * qb.x), r1 = wsum64(yv * qb.y);
    float r2 = wsum64(yv * qb.z), r3 = wsum64(yv * qb.w);
    if (lane == 0) {
      *(float4*)&eln[n << 2] = make_float4(e0, e1, e2, e3);
      *(float4*)&ern[n << 2] = make_float4(r0, r1, r2, r3);
    }
  }
}

// ---------------- fused layer 1: fp16 gather + f4 GEMV ----------------
__global__ __launch_bounds__(256) void fused_l1_k(
    const __half* __restrict__ x, const float* __restrict__ el,
    const float* __restrict__ er, const float* __restrict__ Wt1,
    const float* __restrict__ b, const float* __restrict__ Qn,
    const int* __restrict__ rp2, const int* __restrict__ csr_src,
    __half* __restrict__ hout, float* __restrict__ eln, float* __restrict__ ern) {
  __shared__ float gs[4][2048];
  int wave = threadIdx.x >> 6, lane = threadIdx.x & 63;
  int q = lane >> 4, r = lane & 15, r8 = r << 3;
  int base = (blockIdx.x * 4 + wave) * 4;
  float* gw = gs[wave];
#pragma unroll 1
  for (int t = 0; t < 4; ++t) {
    int n = RFL(base + t);
    int beg = rp2[n * NB], end = rp2[(n + 1) * NB];  // merged bucket range
    float erq = er[(n << 2) + q];
    float4 aA = make_float4(0.f, 0.f, 0.f, 0.f);
    float4 aB = make_float4(0.f, 0.f, 0.f, 0.f);
    float sw = 0.f;
#define ESTEP(elv, ha)                      \
  do {                                      \
    float4 xa, xb;                          \
    h8tof8((ha), xa, xb);                   \
    float w = __expf(lrelu((elv) + erq));   \
    sw += w;                                \
    aA.x = fmaf(w, xa.x, aA.x);             \
    aA.y = fmaf(w, xa.y, aA.y);             \
    aA.z = fmaf(w, xa.z, aA.z);             \
    aA.w = fmaf(w, xa.w, aA.w);             \
    aB.x = fmaf(w, xb.x, aB.x);             \
    aB.y = fmaf(w, xb.y, aB.y);             \
    aB.z = fmaf(w, xb.z, aB.z);             \
    aB.w = fmaf(w, xb.w, aB.w);             \
  } while (0)
    int j = beg;
    for (; j + 8 <= end; j += 8) {
      int s0 = csr_src[j + 0], s1 = csr_src[j + 1];
      int s2 = csr_src[j + 2], s3 = csr_src[j + 3];
      int s4 = csr_src[j + 4], s5 = csr_src[j + 5];
      int s6 = csr_src[j + 6], s7 = csr_src[j + 7];
      float e0 = el[(s0 << 2) + q], e1 = el[(s1 << 2) + q];
      float e2 = el[(s2 << 2) + q], e3 = el[(s3 << 2) + q];
      float e4 = el[(s4 << 2) + q], e5 = el[(s5 << 2) + q];
      float e6 = el[(s6 << 2) + q], e7 = el[(s7 << 2) + q];
      uint4 hA0 = *(const uint4*)&x[(s0 << 7) + r8];
      uint4 hA1 = *(const uint4*)&x[(s1 << 7) + r8];
      uint4 hA2 = *(const uint4*)&x[(s2 << 7) + r8];
      uint4 hA3 = *(const uint4*)&x[(s3 << 7) + r8];
      uint4 hA4 = *(const uint4*)&x[(s4 << 7) + r8];
      uint4 hA5 = *(const uint4*)&x[(s5 << 7) + r8];
      uint4 hA6 = *(const uint4*)&x[(s6 << 7) + r8];
      uint4 hA7 = *(const uint4*)&x[(s7 << 7) + r8];
      ESTEP(e0, hA0); ESTEP(e1, hA1); ESTEP(e2, hA2); ESTEP(e3, hA3);
      ESTEP(e4, hA4); ESTEP(e5, hA5); ESTEP(e6, hA6); ESTEP(e7, hA7);
    }
    for (; j < end; ++j) {
      int s0 = csr_src[j];
      float e0 = el[(s0 << 2) + q];
      uint4 hA0 = *(const uint4*)&x[(s0 << 7) + r8];
      ESTEP(e0, hA0);
    }
#undef ESTEP
    float inv = sw > 0.f ? 1.0f / sw : 0.f;
    *(float4*)&gw[t * 512 + (q << 7) + r8] =
        make_float4(aA.x * inv, aA.y * inv, aA.z * inv, aA.w * inv);
    *(float4*)&gw[t * 512 + (q << 7) + r8 + 4] =
        make_float4(aB.x * inv, aB.y * inv, aB.z * inv, aB.w * inv);
  }
  // f4 GEMV over 512 rows
  float y0 = 0.f, y1 = 0.f, y2 = 0.f, y3 = 0.f;
  int l4 = lane << 2;
  for (int rr = 0; rr < 512; rr += 4) {
    float4 wv = *(const float4*)&Wt1[(rr << 6) + l4];  // (rr/4)*256 + lane*4
    float4 g0 = *(const float4*)&gw[0 * 512 + rr];
    float4 g1 = *(const float4*)&gw[1 * 512 + rr];
    float4 g2 = *(const float4*)&gw[2 * 512 + rr];
    float4 g3 = *(const float4*)&gw[3 * 512 + rr];
    y0 = fmaf(g0.x, wv.x, y0); y0 = fmaf(g0.y, wv.y, y0);
    y0 = fmaf(g0.z, wv.z, y0); y0 = fmaf(g0.w, wv.w, y0);
    y1 = fmaf(g1.x, wv.x, y1); y1 = fmaf(g1.y, wv.y, y1);
    y1 = fmaf(g1.z, wv.z, y1); y1 = fmaf(g1.w, wv.w, y1);
    y2 = fmaf(g2.x, wv.x, y2); y2 = fmaf(g2.y, wv.y, y2);
    y2 = fmaf(g2.z, wv.z, y2); y2 = fmaf(g2.w, wv.w, y2);
    y3 = fmaf(g3.x, wv.x, y3); y3 = fmaf(g3.y, wv.y, y3);
    y3 = fmaf(g3.z, wv.z, y3); y3 = fmaf(g3.w, wv.w, y3);
  }
  float bsum = b[lane] + b[64 + lane] + b[128 + lane] + b[192 + lane];
  float4 qa = *(const float4*)&Qn[lane * 8];
  float4 qb = *(const float4*)&Qn[lane * 8 + 4];
  float ys[4] = {y0, y1, y2, y3};
#pragma unroll
  for (int t = 0; t < 4; ++t) {
    int n = base + t;
    float yv = 0.25f * (ys[t] + bsum);
    hout[(n << 6) + lane] = __float2half(yv);
    float e0 = wsum64(yv * qa.x), e1 = wsum64(yv * qa.y);
    float e2 = wsum64(yv * qa.z), e3 = wsum64(yv * qa.w);
    float r0 = wsum64(yv * qb.x), r1 = wsum64(yv * qb.y);
    float r2 = wsum64(yv * qb.z), r3 = wsum64(yv * qb.w);
    if (lane == 0) {
      *(float4*)&eln[n << 2] = make_float4(e0, e1, e2, e3);
      *(float4*)&ern[n << 2] = make_float4(r0, r1, r2, r3);
    }
  }
}

// ---------------- fused final (bucketed fp16 agg + f4 GEMV(Mt) + LayerNorm) ----
__global__ __launch_bounds__(256) void fused_final_k(
    const __half* __restrict__ x, const float* __restrict__ el,
    const float* __restrict__ er, const float* __restrict__ Mt,
    const float* __restrict__ cvec, const int* __restrict__ rp2,
    const int* __restrict__ csr_src, float* __restrict__ out) {
  __shared__ float gs[4][1024];
  int wave = threadIdx.x >> 6, lane = threadIdx.x & 63;
  int q = lane >> 4, r = lane & 15, r4 = r << 2;
  int base = (blockIdx.x * 4 + wave) * 4;
  float* gw = gs[wave];
  float4 av[4];
  float swv[4], erqv[4];
#pragma unroll
  for (int t = 0; t < 4; ++t) {
    av[t] = make_float4(0.f, 0.f, 0.f, 0.f);
    swv[t] = 0.f;
    erqv[t] = er[((base + t) << 2) + q];
  }
#pragma unroll 1
  for (int bkt = 0; bkt < NB; ++bkt) {
#pragma unroll
    for (int t = 0; t < 4; ++t) {
      int nb = RFL((base + t) * NB + bkt);
      int beg = rp2[nb], end = rp2[nb + 1];
      agg_bucket64(x, el, csr_src, beg, end, q, r4, erqv[t], av[t], swv[t]);
    }
  }
#pragma unroll
  for (int t = 0; t < 4; ++t) {
    float inv = swv[t] > 0.f ? 1.0f / swv[t] : 0.f;
    *(float4*)&gw[t * 256 + (q << 6) + r4] =
        make_float4(av[t].x * inv, av[t].y * inv, av[t].z * inv, av[t].w * inv);
  }
  float y0 = 0.f, y1 = 0.f, y2 = 0.f, y3 = 0.f;
  int l4 = lane << 2;
  for (int rr = 0; rr < 256; rr += 4) {
    float4 wv = *(const float4*)&Mt[(rr << 6) + l4];
    float4 g0 = *(const float4*)&gw[0 * 256 + rr];
    float4 g1 = *(const float4*)&gw[1 * 256 + rr];
    float4 g2 = *(const float4*)&gw[2 * 256 + rr];
    float4 g3 = *(const float4*)&gw[3 * 256 + rr];
    y0 = fmaf(g0.x, wv.x, y0); y0 = fmaf(g0.y, wv.y, y0);
    y0 = fmaf(g0.z, wv.z, y0); y0 = fmaf(g0.w, wv.w, y0);
    y1 = fmaf(g1.x, wv.x, y1); y1 = fmaf(g1.y, wv.y, y1);
    y1 = fmaf(g1.z, wv.z, y1); y1 = fmaf(g1.w, wv.w, y1);
    y2 = fmaf(g2.x, wv.x, y2); y2 = fmaf(g2.y, wv.y, y2);
    y2 = fmaf(g2.z, wv.z, y2); y2 = fmaf(g2.w, wv.w, y2);
    y3 = fmaf(g3.x, wv.x, y3); y3 = fmaf(g3.y, wv.y, y3);
    y3 = fmaf(g3.z, wv.z, y3); y3 = fmaf(g3.w, wv.w, y3);
  }
  float cl = cvec[lane];
  float ys[4] = {y0 + cl, y1 + cl, y2 + cl, y3 + cl};
#pragma unroll
  for (int t = 0; t < 4; ++t) {
    int n = base + t;
    float y = ys[t];
    float mu = wsum64(y) * (1.0f / 64.0f);
    float dv = y - mu;
    float var = wsum64(dv * dv) * (1.0f / 64.0f);
    out[(n << 6) + lane] = dv * rsqrtf(var + 1e-5f);
  }
}

// ---------------- launch ----------------
extern "C" void kernel_launch(void* const* d_in, const int* in_sizes, int n_in,
                              void* d_out, int out_size, void* d_ws, size_t ws_size,
                              hipStream_t stream) {
  const float* in_feat = (const float*)d_in[0];
  const int* src = (const int*)d_in[1];
  const int* dst = (const int*)d_in[2];
  const float* W1 = (const float*)d_in[3];
  const float* al1 = (const float*)d_in[4];
  const float* ar1 = (const float*)d_in[5];
  const float* b1 = (const float*)d_in[6];
  const float* Wh = (const float*)d_in[7];   // [3][64][256]
  const float* alh = (const float*)d_in[8];  // [3][4][64]
  const float* arh = (const float*)d_in[9];  // [3][4][64]
  const float* bh = (const float*)d_in[10];  // [3][256]
  const float* Wo = (const float*)d_in[11];  // [256][64]
  const float* bo = (const float*)d_in[12];  // [64]
  float* out = (float*)d_out;

  char* ws = (char*)d_ws;
  size_t off = 0;
  auto alloc = [&](size_t bytes) {
    void* p = ws + off;
    off = (off + bytes + 255) & ~(size_t)255;
    return p;
  };
  __half* x16 = (__half*)alloc((size_t)NN * 128 * 2);
  __half* h_a = (__half*)alloc((size_t)NN * 64 * 2);
  __half* h_b = (__half*)alloc((size_t)NN * 64 * 2);
  float* el_a = (float*)alloc((size_t)NN * 4 * 4);
  float* er_a = (float*)alloc((size_t)NN * 4 * 4);
  float* el_b = (float*)alloc((size_t)NN * 4 * 4);
  float* er_b = (float*)alloc((size_t)NN * 4 * 4);
  float* Q1 = (float*)alloc(128 * 8 * 4);
  float* Q2 = (float*)alloc(64 * 8 * 4);
  float* Q3 = (float*)alloc(64 * 8 * 4);
  float* Q4 = (float*)alloc(64 * 8 * 4);
  float* M = (float*)alloc(256 * 64 * 4);
  float* Mt = (float*)alloc(256 * 64 * 4);
  float* Wt1 = (float*)alloc(512 * 64 * 4);
  float* Wth = (float*)alloc(3 * 256 * 64 * 4);
  float* cvec = (float*)alloc(64 * 4);
  int* deg2 = (int*)alloc((size_t)NR2 * 4);
  int* rp2 = (int*)alloc((size_t)(NR2 + 1) * 4);
  int* cur2 = (int*)alloc((size_t)NR2 * 4);
  int* part = (int*)alloc((size_t)SCAN_BLOCKS * 4);
  int* csr_src = (int*)alloc((size_t)NE * 4);
  (void)ws_size; (void)in_sizes; (void)n_in; (void)out_size;

  // bucketed CSR build (hierarchical scan)
  zero_int_k<<<(NR2 + 255) / 256, 256, 0, stream>>>(deg2, NR2);
  count_deg2_k<<<(NE + 255) / 256, 256, 0, stream>>>(src, dst, deg2);
  scan_part_k<<<SCAN_BLOCKS, 1024, 0, stream>>>(deg2, part);
  scan_mid_k<<<1, 256, 0, stream>>>(part, rp2);
  scan_apply_k<<<SCAN_BLOCKS, 1024, 0, stream>>>(deg2, part, rp2, cur2);
  fill_csr2_k<<<(NE + 255) / 256, 256, 0, stream>>>(src, dst, cur2, csr_src);

  // in_feat -> fp16
  cvt_x_k<<<(NN * 128 / 4 + 255) / 256, 256, 0, stream>>>(in_feat, x16, NN * 128 / 4);

  // tiny precomputes
  compute_q_k<<<4, 256, 0, stream>>>(W1, al1, ar1, Q1, 128);
  compute_q_k<<<2, 256, 0, stream>>>(Wh + 0 * 64 * 256, alh + 0 * 256, arh + 0 * 256, Q2, 64);
  compute_q_k<<<2, 256, 0, stream>>>(Wh + 1 * 64 * 256, alh + 1 * 256, arh + 1 * 256, Q3, 64);
  compute_q_k<<<2, 256, 0, stream>>>(Wh + 2 * 64 * 256, alh + 2 * 256, arh + 2 * 256, Q4, 64);
  compute_m_k<<<256, 64, 0, stream>>>(Wh + 2 * 64 * 256, Wo, M);
  compute_c_k<<<1, 64, 0, stream>>>(bh + 2 * 256, Wo, bo, cvec);
  // block-transposed weights for f4 GEMVs
  tr_w1_k<<<128, 256, 0, stream>>>(W1, Wt1);
  tr_wh_k<<<192, 256, 0, stream>>>(Wh, Wth);
  tr_m_k<<<64, 256, 0, stream>>>(M, Mt);

  const int FUSED_GRID = NN / 16;  // 3125
  const int ELER_GRID = NN / 4;    // 12500

  // layer 1
  eler_l1_k<<<ELER_GRID, 256, 0, stream>>>(in_feat, Q1, el_a, er_a);
  fused_l1_k<<<FUSED_GRID, 256, 0, stream>>>(x16, el_a, er_a, Wt1, b1, Q2,
                                             rp2, csr_src, h_a, el_b, er_b);
  // hidden layers
  fused_hidden_k<<<FUSED_GRID, 256, 0, stream>>>(h_a, el_b, er_b, Wth + 0 * 16384,
                                                 bh + 0 * 256, Q3, rp2, csr_src,
                                                 h_b, el_a, er_a);
  fused_hidden_k<<<FUSED_GRID, 256, 0, stream>>>(h_b, el_a, er_a, Wth + 1 * 16384,
                                                 bh + 1 * 256, Q4, rp2, csr_src,
                                                 h_a, el_b, er_b);
  // final layer + out_ln + LayerNorm
  fused_final_k<<<FUSED_GRID, 256, 0, stream>>>(h_a, el_b, er_b, Mt, cvec,
                                                rp2, csr_src, out);
}

// Round 17
// 550.227 us; speedup vs baseline: 1.0638x; 1.0638x over previous
//
#include <hip/hip_runtime.h>
#include <hip/hip_fp16.h>

#define NN 50000
#define NE 800000
#define NB 4
#define SLICE 12500         // NN/NB
#define NR2 (NN * NB)       // 200000
#define SCAN_BLOCKS ((NR2 + 1023) / 1024)  // 196

// ---------------- wave helpers ----------------
__device__ __forceinline__ float wsum64(float v) {
#pragma unroll
  for (int off = 32; off; off >>= 1) v += __shfl_xor(v, off, 64);
  return v;
}
__device__ __forceinline__ int wisum64(int v) {
#pragma unroll
  for (int off = 32; off; off >>= 1) v += __shfl_xor(v, off, 64);
  return v;
}
__device__ __forceinline__ float lrelu(float x) { return x > 0.0f ? x : 0.2f * x; }
#define RFL(v) __builtin_amdgcn_readfirstlane(v)

// 4 packed halves (8B) -> float4
__device__ __forceinline__ float4 h4tof4(uint2 raw) {
  __half2 a = *reinterpret_cast<const __half2*>(&raw.x);
  __half2 b = *reinterpret_cast<const __half2*>(&raw.y);
  float2 fa = __half22float2(a), fb = __half22float2(b);
  return make_float4(fa.x, fa.y, fb.x, fb.y);
}
// 8 packed halves (16B) -> two float4
__device__ __forceinline__ void h8tof8(uint4 raw, float4& lo, float4& hi) {
  __half2 a = *reinterpret_cast<const __half2*>(&raw.x);
  __half2 b = *reinterpret_cast<const __half2*>(&raw.y);
  __half2 c = *reinterpret_cast<const __half2*>(&raw.z);
  __half2 d = *reinterpret_cast<const __half2*>(&raw.w);
  float2 fa = __half22float2(a), fb = __half22float2(b);
  float2 fc = __half22float2(c), fd = __half22float2(d);
  lo = make_float4(fa.x, fa.y, fb.x, fb.y);
  hi = make_float4(fc.x, fc.y, fd.x, fd.y);
}

// ---------------- fp32 -> fp16 conversion (in_feat) ----------------
__global__ __launch_bounds__(256) void cvt_x_k(const float* __restrict__ in,
                                               __half* __restrict__ out, int n4) {
  int i = blockIdx.x * 256 + threadIdx.x;
  if (i >= n4) return;
  float4 v = *(const float4*)&in[i << 2];
  __half2 a = __floats2half2_rn(v.x, v.y);
  __half2 b = __floats2half2_rn(v.z, v.w);
  uint2 p;
  p.x = *reinterpret_cast<const unsigned int*>(&a);
  p.y = *reinterpret_cast<const unsigned int*>(&b);
  *(uint2*)&out[i << 2] = p;
}

// ---------------- CSR build (bucketed by src slice) ----------------
__global__ void zero_int_k(int* __restrict__ p, int n) {
  int i = blockIdx.x * 256 + threadIdx.x;
  if (i < n) p[i] = 0;
}

__global__ void count_deg2_k(const int* __restrict__ src, const int* __restrict__ dst,
                             int* __restrict__ deg2) {
  int e = blockIdx.x * 256 + threadIdx.x;
  if (e < NE) {
    int b = src[e] / SLICE;
    atomicAdd(&deg2[dst[e] * NB + b], 1);
  }
}

// (a) per-block sums
__global__ __launch_bounds__(1024) void scan_part_k(const int* __restrict__ deg2,
                                                    int* __restrict__ part) {
  __shared__ int ws[16];
  int tid = threadIdx.x, w = tid >> 6;
  int i = blockIdx.x * 1024 + tid;
  int v = (i < NR2) ? deg2[i] : 0;
  int s = wisum64(v);
  if ((tid & 63) == 0) ws[w] = s;
  __syncthreads();
  if (tid == 0) {
    int tot = 0;
#pragma unroll
    for (int u = 0; u < 16; ++u) tot += ws[u];
    part[blockIdx.x] = tot;
  }
}

// (b) scan the 196 partials (one small block)
__global__ void scan_mid_k(int* __restrict__ part, int* __restrict__ rp2) {
  __shared__ int sh[256];
  int tid = threadIdx.x;
  int v = (tid < SCAN_BLOCKS) ? part[tid] : 0;
  sh[tid] = v;
  __syncthreads();
  for (int off = 1; off < 256; off <<= 1) {
    int t = (tid >= off) ? sh[tid - off] : 0;
    __syncthreads();
    sh[tid] += t;
    __syncthreads();
  }
  int incl = sh[tid];
  if (tid < SCAN_BLOCKS) part[tid] = incl - v;  // exclusive
  if (tid == SCAN_BLOCKS - 1) rp2[NR2] = incl;  // total == NE
}

// (c) local scan + block offset -> rp2 / cur2
__global__ __launch_bounds__(1024) void scan_apply_k(const int* __restrict__ deg2,
                                                     const int* __restrict__ part,
                                                     int* __restrict__ rp2,
                                                     int* __restrict__ cur2) {
  __shared__ int ws[16];
  int tid = threadIdx.x, lane = tid & 63, w = tid >> 6;
  int i = blockIdx.x * 1024 + tid;
  int v = (i < NR2) ? deg2[i] : 0;
  int incl = v;
#pragma unroll
  for (int off = 1; off < 64; off <<= 1) {
    int t = __shfl_up(incl, off, 64);
    if (lane >= off) incl += t;
  }
  if (lane == 63) ws[w] = incl;
  __syncthreads();
  if (tid == 0) {
    int run = 0;
#pragma unroll
    for (int u = 0; u < 16; ++u) { int t = ws[u]; ws[u] = run; run += t; }
  }
  __syncthreads();
  int excl = incl - v + ws[w] + part[blockIdx.x];
  if (i < NR2) {
    rp2[i] = excl;
    cur2[i] = excl;
  }
}

__global__ void fill_csr2_k(const int* __restrict__ src, const int* __restrict__ dst,
                            int* __restrict__ cur2, int* __restrict__ csr_src) {
  int e = blockIdx.x * 256 + threadIdx.x;
  if (e < NE) {
    int sv = src[e];
    int b = sv / SLICE;
    int pos = atomicAdd(&cur2[dst[e] * NB + b], 1);
    csr_src[pos] = sv;
  }
}

// ---------------- tiny precomputes ----------------
__global__ void compute_q_k(const float* __restrict__ W, const float* __restrict__ al,
                            const float* __restrict__ ar, float* __restrict__ Q, int KDIM) {
  int idx = blockIdx.x * 256 + threadIdx.x;
  if (idx >= KDIM * 8) return;
  int k = idx >> 3, c = idx & 7;
  int h = c & 3;
  const float* av = (c < 4 ? al : ar) + h * 64;
  const float* wrow = W + (size_t)k * 256 + h * 64;
  float s = 0.0f;
  for (int m = 0; m < 64; ++m) s += wrow[m] * av[m];
  Q[idx] = s;
}

__global__ void compute_m_k(const float* __restrict__ Wh2, const float* __restrict__ Wo,
                            float* __restrict__ M) {
  int row = blockIdx.x;  // 0..255
  int d = threadIdx.x;   // 0..63
  int h = row >> 6, k = row & 63;
  float s = 0.0f;
  for (int j = 0; j < 64; ++j)
    s += Wh2[k * 256 + h * 64 + j] * Wo[(h * 64 + j) * 64 + d];
  M[row * 64 + d] = s;
}

__global__ void compute_c_k(const float* __restrict__ bh2, const float* __restrict__ Wo,
                            const float* __restrict__ bo, float* __restrict__ cvec) {
  int d = threadIdx.x;
  if (d >= 64) return;
  float s = bo[d];
  for (int m = 0; m < 256; ++m) s += bh2[m] * Wo[m * 64 + d];
  cvec[d] = s;
}

// ---------------- el/er for layer 1 (fp32 input, exact) ----------------
__global__ __launch_bounds__(256) void eler_l1_k(const float* __restrict__ X,
                                                 const float* __restrict__ Q,
                                                 float* __restrict__ elp,
                                                 float* __restrict__ erp) {
  int n = RFL(blockIdx.x * 4 + (threadIdx.x >> 6));
  int lane = threadIdx.x & 63;
  float2 xv = *(const float2*)&X[(n << 7) + (lane << 1)];
  float4 qa0 = *(const float4*)&Q[(lane * 2) * 8];
  float4 qb0 = *(const float4*)&Q[(lane * 2) * 8 + 4];
  float4 qa1 = *(const float4*)&Q[(lane * 2 + 1) * 8];
  float4 qb1 = *(const float4*)&Q[(lane * 2 + 1) * 8 + 4];
  float p[8];
  p[0] = xv.x * qa0.x + xv.y * qa1.x; p[1] = xv.x * qa0.y + xv.y * qa1.y;
  p[2] = xv.x * qa0.z + xv.y * qa1.z; p[3] = xv.x * qa0.w + xv.y * qa1.w;
  p[4] = xv.x * qb0.x + xv.y * qb1.x; p[5] = xv.x * qb0.y + xv.y * qb1.y;
  p[6] = xv.x * qb0.z + xv.y * qb1.z; p[7] = xv.x * qb0.w + xv.y * qb1.w;
#pragma unroll
  for (int c = 0; c < 8; ++c) p[c] = wsum64(p[c]);
  if (lane == 0) {
    *(float4*)&elp[n << 2] = make_float4(p[0], p[1], p[2], p[3]);
    *(float4*)&erp[n << 2] = make_float4(p[4], p[5], p[6], p[7]);
  }
}

// ---------------- bucket edge-loop body (64-dim, fp16 x) ----------------
__device__ __forceinline__ void agg_bucket64(const __half* __restrict__ x,
                                             const float* __restrict__ el,
                                             const int* __restrict__ csr,
                                             int beg, int end, int q, int r4,
                                             float erq, float4& a, float& sw) {
  int j = beg;
  for (; j + 4 <= end; j += 4) {
    int s0 = csr[j + 0], s1 = csr[j + 1], s2 = csr[j + 2], s3 = csr[j + 3];
    float e0 = el[(s0 << 2) + q], e1 = el[(s1 << 2) + q];
    float e2 = el[(s2 << 2) + q], e3 = el[(s3 << 2) + q];
    uint2 h0 = *(const uint2*)&x[(s0 << 6) + r4];
    uint2 h1 = *(const uint2*)&x[(s1 << 6) + r4];
    uint2 h2 = *(const uint2*)&x[(s2 << 6) + r4];
    uint2 h3 = *(const uint2*)&x[(s3 << 6) + r4];
    float4 x0 = h4tof4(h0);
    float4 x1 = h4tof4(h1);
    float4 x2 = h4tof4(h2);
    float4 x3 = h4tof4(h3);
    float w0 = __expf(lrelu(e0 + erq)), w1 = __expf(lrelu(e1 + erq));
    float w2 = __expf(lrelu(e2 + erq)), w3 = __expf(lrelu(e3 + erq));
    sw += w0 + w1 + w2 + w3;
    a.x = fmaf(w0, x0.x, a.x); a.y = fmaf(w0, x0.y, a.y);
    a.z = fmaf(w0, x0.z, a.z); a.w = fmaf(w0, x0.w, a.w);
    a.x = fmaf(w1, x1.x, a.x); a.y = fmaf(w1, x1.y, a.y);
    a.z = fmaf(w1, x1.z, a.z); a.w = fmaf(w1, x1.w, a.w);
    a.x = fmaf(w2, x2.x, a.x); a.y = fmaf(w2, x2.y, a.y);
    a.z = fmaf(w2, x2.z, a.z); a.w = fmaf(w2, x2.w, a.w);
    a.x = fmaf(w3, x3.x, a.x); a.y = fmaf(w3, x3.y, a.y);
    a.z = fmaf(w3, x3.z, a.z); a.w = fmaf(w3, x3.w, a.w);
  }
  for (; j < end; ++j) {
    int s0 = csr[j];
    float e0 = el[(s0 << 2) + q];
    uint2 h0 = *(const uint2*)&x[(s0 << 6) + r4];
    float4 x0 = h4tof4(h0);
    float w0 = __expf(lrelu(e0 + erq));
    sw += w0;
    a.x = fmaf(w0, x0.x, a.x); a.y = fmaf(w0, x0.y, a.y);
    a.z = fmaf(w0, x0.z, a.z); a.w = fmaf(w0, x0.w, a.w);
  }
}

// ---------------- fused hidden layer (bucketed fp16 agg + R5 GEMV) -------------
__global__ __launch_bounds__(256) void fused_hidden_k(
    const __half* __restrict__ x, const float* __restrict__ el,
    const float* __restrict__ er, const float* __restrict__ W,
    const float* __restrict__ b, const float* __restrict__ Qn,
    const int* __restrict__ rp2, const int* __restrict__ csr_src,
    __half* __restrict__ hout, float* __restrict__ eln, float* __restrict__ ern) {
  __shared__ float gs[4][1024];
  int wave = threadIdx.x >> 6, lane = threadIdx.x & 63;
  int q = lane >> 4, r = lane & 15, r4 = r << 2;
  int base = (blockIdx.x * 4 + wave) * 4;
  float* gw = gs[wave];
  float4 av[4];
  float swv[4], erqv[4];
#pragma unroll
  for (int t = 0; t < 4; ++t) {
    av[t] = make_float4(0.f, 0.f, 0.f, 0.f);
    swv[t] = 0.f;
    erqv[t] = er[((base + t) << 2) + q];
  }
#pragma unroll 1
  for (int bkt = 0; bkt < NB; ++bkt) {
#pragma unroll
    for (int t = 0; t < 4; ++t) {
      int nb = RFL((base + t) * NB + bkt);
      int beg = rp2[nb], end = rp2[nb + 1];
      agg_bucket64(x, el, csr_src, beg, end, q, r4, erqv[t], av[t], swv[t]);
    }
  }
#pragma unroll
  for (int t = 0; t < 4; ++t) {
    float inv = swv[t] > 0.f ? 1.0f / swv[t] : 0.f;
    *(float4*)&gw[t * 256 + (q << 6) + r4] =
        make_float4(av[t].x * inv, av[t].y * inv, av[t].z * inv, av[t].w * inv);
  }
  float y0 = 0.f, y1 = 0.f, y2 = 0.f, y3 = 0.f;
  for (int rr = 0; rr < 256; rr += 4) {
#pragma unroll
    for (int u = 0; u < 4; ++u) {
      int row = rr + u;
      int h = row >> 6, k = row & 63;
      float sv = W[k * 256 + (h << 6) + lane];
      y0 = fmaf(gw[0 * 256 + row], sv, y0);
      y1 = fmaf(gw[1 * 256 + row], sv, y1);
      y2 = fmaf(gw[2 * 256 + row], sv, y2);
      y3 = fmaf(gw[3 * 256 + row], sv, y3);
    }
  }
  float bsum = b[lane] + b[64 + lane] + b[128 + lane] + b[192 + lane];
  float4 qa = *(const float4*)&Qn[lane * 8];
  float4 qb = *(const float4*)&Qn[lane * 8 + 4];
  float ys[4] = {y0, y1, y2, y3};
#pragma unroll
  for (int t = 0; t < 4; ++t) {
    int n = base + t;
    float yv = 0.25f * (ys[t] + bsum);
    hout[(n << 6) + lane] = __float2half(yv);
    float e0 = wsum64(yv * qa.x), e1 = wsum64(yv * qa.y);
    float e2 = wsum64(yv * qa.z), e3 = wsum64(yv * qa.w);
    float r0 = wsum64(yv * qb.x), r1 = wsum64(yv * qb.y);
    float r2 = wsum64(yv * qb.z), r3 = wsum64(yv * qb.w);
    if (lane == 0) {
      *(float4*)&eln[n << 2] = make_float4(e0, e1, e2, e3);
      *(float4*)&ern[n << 2] = make_float4(r0, r1, r2, r3);
    }
  }
}

// ---------------- fused layer 1: fp16 gather, merged range, 8-edge unroll ------
__global__ __launch_bounds__(256) void fused_l1_k(
    const __half* __restrict__ x, const float* __restrict__ el,
    const float* __restrict__ er, const float* __restrict__ W,
    const float* __restrict__ b, const float* __restrict__ Qn,
    const int* __restrict__ rp2, const int* __restrict__ csr_src,
    __half* __restrict__ hout, float* __restrict__ eln, float* __restrict__ ern) {
  __shared__ float gs[4][2048];
  int wave = threadIdx.x >> 6, lane = threadIdx.x & 63;
  int q = lane >> 4, r = lane & 15, r8 = r << 3;
  int base = (blockIdx.x * 4 + wave) * 4;
  float* gw = gs[wave];
#pragma unroll 1
  for (int t = 0; t < 4; ++t) {
    int n = RFL(base + t);
    int beg = rp2[n * NB], end = rp2[(n + 1) * NB];  // merged bucket range
    float erq = er[(n << 2) + q];
    float4 aA = make_float4(0.f, 0.f, 0.f, 0.f);
    float4 aB = make_float4(0.f, 0.f, 0.f, 0.f);
    float sw = 0.f;
#define ESTEP(elv, ha)                      \
  do {                                      \
    float4 xa, xb;                          \
    h8tof8((ha), xa, xb);                   \
    float w = __expf(lrelu((elv) + erq));   \
    sw += w;                                \
    aA.x = fmaf(w, xa.x, aA.x);             \
    aA.y = fmaf(w, xa.y, aA.y);             \
    aA.z = fmaf(w, xa.z, aA.z);             \
    aA.w = fmaf(w, xa.w, aA.w);             \
    aB.x = fmaf(w, xb.x, aB.x);             \
    aB.y = fmaf(w, xb.y, aB.y);             \
    aB.z = fmaf(w, xb.z, aB.z);             \
    aB.w = fmaf(w, xb.w, aB.w);             \
  } while (0)
    int j = beg;
    for (; j + 8 <= end; j += 8) {
      int s0 = csr_src[j + 0], s1 = csr_src[j + 1];
      int s2 = csr_src[j + 2], s3 = csr_src[j + 3];
      int s4 = csr_src[j + 4], s5 = csr_src[j + 5];
      int s6 = csr_src[j + 6], s7 = csr_src[j + 7];
      float e0 = el[(s0 << 2) + q], e1 = el[(s1 << 2) + q];
      float e2 = el[(s2 << 2) + q], e3 = el[(s3 << 2) + q];
      float e4 = el[(s4 << 2) + q], e5 = el[(s5 << 2) + q];
      float e6 = el[(s6 << 2) + q], e7 = el[(s7 << 2) + q];
      uint4 hA0 = *(const uint4*)&x[(s0 << 7) + r8];
      uint4 hA1 = *(const uint4*)&x[(s1 << 7) + r8];
      uint4 hA2 = *(const uint4*)&x[(s2 << 7) + r8];
      uint4 hA3 = *(const uint4*)&x[(s3 << 7) + r8];
      uint4 hA4 = *(const uint4*)&x[(s4 << 7) + r8];
      uint4 hA5 = *(const uint4*)&x[(s5 << 7) + r8];
      uint4 hA6 = *(const uint4*)&x[(s6 << 7) + r8];
      uint4 hA7 = *(const uint4*)&x[(s7 << 7) + r8];
      ESTEP(e0, hA0); ESTEP(e1, hA1); ESTEP(e2, hA2); ESTEP(e3, hA3);
      ESTEP(e4, hA4); ESTEP(e5, hA5); ESTEP(e6, hA6); ESTEP(e7, hA7);
    }
    for (; j < end; ++j) {
      int s0 = csr_src[j];
      float e0 = el[(s0 << 2) + q];
      uint4 hA0 = *(const uint4*)&x[(s0 << 7) + r8];
      ESTEP(e0, hA0);
    }
#undef ESTEP
    float inv = sw > 0.f ? 1.0f / sw : 0.f;
    *(float4*)&gw[t * 512 + (q << 7) + r8] =
        make_float4(aA.x * inv, aA.y * inv, aA.z * inv, aA.w * inv);
    *(float4*)&gw[t * 512 + (q << 7) + r8 + 4] =
        make_float4(aB.x * inv, aB.y * inv, aB.z * inv, aB.w * inv);
  }
  // GEMV: row = h*128+k, sv = W[k*256 + h*64 + lane]
  float y0 = 0.f, y1 = 0.f, y2 = 0.f, y3 = 0.f;
  for (int rr = 0; rr < 512; rr += 4) {
#pragma unroll
    for (int u = 0; u < 4; ++u) {
      int row = rr + u;
      int h = row >> 7, k = row & 127;
      float sv = W[k * 256 + (h << 6) + lane];
      y0 = fmaf(gw[0 * 512 + row], sv, y0);
      y1 = fmaf(gw[1 * 512 + row], sv, y1);
      y2 = fmaf(gw[2 * 512 + row], sv, y2);
      y3 = fmaf(gw[3 * 512 + row], sv, y3);
    }
  }
  float bsum = b[lane] + b[64 + lane] + b[128 + lane] + b[192 + lane];
  float4 qa = *(const float4*)&Qn[lane * 8];
  float4 qb = *(const float4*)&Qn[lane * 8 + 4];
  float ys[4] = {y0, y1, y2, y3};
#pragma unroll
  for (int t = 0; t < 4; ++t) {
    int n = base + t;
    float yv = 0.25f * (ys[t] + bsum);
    hout[(n << 6) + lane] = __float2half(yv);
    float e0 = wsum64(yv * qa.x), e1 = wsum64(yv * qa.y);
    float e2 = wsum64(yv * qa.z), e3 = wsum64(yv * qa.w);
    float r0 = wsum64(yv * qb.x), r1 = wsum64(yv * qb.y);
    float r2 = wsum64(yv * qb.z), r3 = wsum64(yv * qb.w);
    if (lane == 0) {
      *(float4*)&eln[n << 2] = make_float4(e0, e1, e2, e3);
      *(float4*)&ern[n << 2] = make_float4(r0, r1, r2, r3);
    }
  }
}

// ---------------- fused final (bucketed fp16 agg + GEMV(M) + LayerNorm) --------
__global__ __launch_bounds__(256) void fused_final_k(
    const __half* __restrict__ x, const float* __restrict__ el,
    const float* __restrict__ er, const float* __restrict__ M,
    const float* __restrict__ cvec, const int* __restrict__ rp2,
    const int* __restrict__ csr_src, float* __restrict__ out) {
  __shared__ float gs[4][1024];
  int wave = threadIdx.x >> 6, lane = threadIdx.x & 63;
  int q = lane >> 4, r = lane & 15, r4 = r << 2;
  int base = (blockIdx.x * 4 + wave) * 4;
  float* gw = gs[wave];
  float4 av[4];
  float swv[4], erqv[4];
#pragma unroll
  for (int t = 0; t < 4; ++t) {
    av[t] = make_float4(0.f, 0.f, 0.f, 0.f);
    swv[t] = 0.f;
    erqv[t] = er[((base + t) << 2) + q];
  }
#pragma unroll 1
  for (int bkt = 0; bkt < NB; ++bkt) {
#pragma unroll
    for (int t = 0; t < 4; ++t) {
      int nb = RFL((base + t) * NB + bkt);
      int beg = rp2[nb], end = rp2[nb + 1];
      agg_bucket64(x, el, csr_src, beg, end, q, r4, erqv[t], av[t], swv[t]);
    }
  }
#pragma unroll
  for (int t = 0; t < 4; ++t) {
    float inv = swv[t] > 0.f ? 1.0f / swv[t] : 0.f;
    *(float4*)&gw[t * 256 + (q << 6) + r4] =
        make_float4(av[t].x * inv, av[t].y * inv, av[t].z * inv, av[t].w * inv);
  }
  float y0 = 0.f, y1 = 0.f, y2 = 0.f, y3 = 0.f;
  for (int rr = 0; rr < 256; rr += 4) {
#pragma unroll
    for (int u = 0; u < 4; ++u) {
      int row = rr + u;
      float sv = M[(row << 6) + lane];
      y0 = fmaf(gw[0 * 256 + row], sv, y0);
      y1 = fmaf(gw[1 * 256 + row], sv, y1);
      y2 = fmaf(gw[2 * 256 + row], sv, y2);
      y3 = fmaf(gw[3 * 256 + row], sv, y3);
    }
  }
  float cl = cvec[lane];
  float ys[4] = {y0 + cl, y1 + cl, y2 + cl, y3 + cl};
#pragma unroll
  for (int t = 0; t < 4; ++t) {
    int n = base + t;
    float y = ys[t];
    float mu = wsum64(y) * (1.0f / 64.0f);
    float dv = y - mu;
    float var = wsum64(dv * dv) * (1.0f / 64.0f);
    out[(n << 6) + lane] = dv * rsqrtf(var + 1e-5f);
  }
}

// ---------------- launch ----------------
extern "C" void kernel_launch(void* const* d_in, const int* in_sizes, int n_in,
                              void* d_out, int out_size, void* d_ws, size_t ws_size,
                              hipStream_t stream) {
  const float* in_feat = (const float*)d_in[0];
  const int* src = (const int*)d_in[1];
  const int* dst = (const int*)d_in[2];
  const float* W1 = (const float*)d_in[3];
  const float* al1 = (const float*)d_in[4];
  const float* ar1 = (const float*)d_in[5];
  const float* b1 = (const float*)d_in[6];
  const float* Wh = (const float*)d_in[7];   // [3][64][256]
  const float* alh = (const float*)d_in[8];  // [3][4][64]
  const float* arh = (const float*)d_in[9];  // [3][4][64]
  const float* bh = (const float*)d_in[10];  // [3][256]
  const float* Wo = (const float*)d_in[11];  // [256][64]
  const float* bo = (const float*)d_in[12];  // [64]
  float* out = (float*)d_out;

  char* ws = (char*)d_ws;
  size_t off = 0;
  auto alloc = [&](size_t bytes) {
    void* p = ws + off;
    off = (off + bytes + 255) & ~(size_t)255;
    return p;
  };
  __half* x16 = (__half*)alloc((size_t)NN * 128 * 2);
  __half* h_a = (__half*)alloc((size_t)NN * 64 * 2);
  __half* h_b = (__half*)alloc((size_t)NN * 64 * 2);
  float* el_a = (float*)alloc((size_t)NN * 4 * 4);
  float* er_a = (float*)alloc((size_t)NN * 4 * 4);
  float* el_b = (float*)alloc((size_t)NN * 4 * 4);
  float* er_b = (float*)alloc((size_t)NN * 4 * 4);
  float* Q1 = (float*)alloc(128 * 8 * 4);
  float* Q2 = (float*)alloc(64 * 8 * 4);
  float* Q3 = (float*)alloc(64 * 8 * 4);
  float* Q4 = (float*)alloc(64 * 8 * 4);
  float* M = (float*)alloc(256 * 64 * 4);
  float* cvec = (float*)alloc(64 * 4);
  int* deg2 = (int*)alloc((size_t)NR2 * 4);
  int* rp2 = (int*)alloc((size_t)(NR2 + 1) * 4);
  int* cur2 = (int*)alloc((size_t)NR2 * 4);
  int* part = (int*)alloc((size_t)SCAN_BLOCKS * 4);
  int* csr_src = (int*)alloc((size_t)NE * 4);
  (void)ws_size; (void)in_sizes; (void)n_in; (void)out_size;

  // bucketed CSR build (hierarchical scan)
  zero_int_k<<<(NR2 + 255) / 256, 256, 0, stream>>>(deg2, NR2);
  count_deg2_k<<<(NE + 255) / 256, 256, 0, stream>>>(src, dst, deg2);
  scan_part_k<<<SCAN_BLOCKS, 1024, 0, stream>>>(deg2, part);
  scan_mid_k<<<1, 256, 0, stream>>>(part, rp2);
  scan_apply_k<<<SCAN_BLOCKS, 1024, 0, stream>>>(deg2, part, rp2, cur2);
  fill_csr2_k<<<(NE + 255) / 256, 256, 0, stream>>>(src, dst, cur2, csr_src);

  // in_feat -> fp16
  cvt_x_k<<<(NN * 128 / 4 + 255) / 256, 256, 0, stream>>>(in_feat, x16, NN * 128 / 4);

  // tiny precomputes
  compute_q_k<<<4, 256, 0, stream>>>(W1, al1, ar1, Q1, 128);
  compute_q_k<<<2, 256, 0, stream>>>(Wh + 0 * 64 * 256, alh + 0 * 256, arh + 0 * 256, Q2, 64);
  compute_q_k<<<2, 256, 0, stream>>>(Wh + 1 * 64 * 256, alh + 1 * 256, arh + 1 * 256, Q3, 64);
  compute_q_k<<<2, 256, 0, stream>>>(Wh + 2 * 64 * 256, alh + 2 * 256, arh + 2 * 256, Q4, 64);
  compute_m_k<<<256, 64, 0, stream>>>(Wh + 2 * 64 * 256, Wo, M);
  compute_c_k<<<1, 64, 0, stream>>>(bh + 2 * 256, Wo, bo, cvec);

  const int FUSED_GRID = NN / 16;  // 3125
  const int ELER_GRID = NN / 4;    // 12500

  // layer 1
  eler_l1_k<<<ELER_GRID, 256, 0, stream>>>(in_feat, Q1, el_a, er_a);
  fused_l1_k<<<FUSED_GRID, 256, 0, stream>>>(x16, el_a, er_a, W1, b1, Q2,
                                             rp2, csr_src, h_a, el_b, er_b);
  // hidden layers
  fused_hidden_k<<<FUSED_GRID, 256, 0, stream>>>(h_a, el_b, er_b, Wh + 0 * 64 * 256,
                                                 bh + 0 * 256, Q3, rp2, csr_src,
                                                 h_b, el_a, er_a);
  fused_hidden_k<<<FUSED_GRID, 256, 0, stream>>>(h_b, el_a, er_a, Wh + 1 * 64 * 256,
                                                 bh + 1 * 256, Q4, rp2, csr_src,
                                                 h_a, el_b, er_b);
  // final layer + out_ln + LayerNorm
  fused_final_k<<<FUSED_GRID, 256, 0, stream>>>(h_a, el_b, er_b, M, cvec,
                                                rp2, csr_src, out);
}

// Round 18
// 539.031 us; speedup vs baseline: 1.0858x; 1.0208x over previous
//
#include <hip/hip_runtime.h>
#include <hip/hip_fp16.h>

#define NN 50000
#define NE 800000
#define NB 4
#define SLICE 12500         // NN/NB
#define NR2 (NN * NB)       // 200000
#define SCAN_BLOCKS ((NR2 + 1023) / 1024)  // 196

// ---------------- wave helpers ----------------
__device__ __forceinline__ float wsum64(float v) {
#pragma unroll
  for (int off = 32; off; off >>= 1) v += __shfl_xor(v, off, 64);
  return v;
}
__device__ __forceinline__ int wisum64(int v) {
#pragma unroll
  for (int off = 32; off; off >>= 1) v += __shfl_xor(v, off, 64);
  return v;
}
__device__ __forceinline__ float lrelu(float x) { return x > 0.0f ? x : 0.2f * x; }
#define RFL(v) __builtin_amdgcn_readfirstlane(v)

// 4 packed halves (8B) -> float4
__device__ __forceinline__ float4 h4tof4(uint2 raw) {
  __half2 a = *reinterpret_cast<const __half2*>(&raw.x);
  __half2 b = *reinterpret_cast<const __half2*>(&raw.y);
  float2 fa = __half22float2(a), fb = __half22float2(b);
  return make_float4(fa.x, fa.y, fb.x, fb.y);
}
// 8 packed halves (16B) -> two float4
__device__ __forceinline__ void h8tof8(uint4 raw, float4& lo, float4& hi) {
  __half2 a = *reinterpret_cast<const __half2*>(&raw.x);
  __half2 b = *reinterpret_cast<const __half2*>(&raw.y);
  __half2 c = *reinterpret_cast<const __half2*>(&raw.z);
  __half2 d = *reinterpret_cast<const __half2*>(&raw.w);
  float2 fa = __half22float2(a), fb = __half22float2(b);
  float2 fc = __half22float2(c), fd = __half22float2(d);
  lo = make_float4(fa.x, fa.y, fb.x, fb.y);
  hi = make_float4(fc.x, fc.y, fd.x, fd.y);
}

// ---------------- fp32 -> fp16 conversion (in_feat) ----------------
__global__ __launch_bounds__(256) void cvt_x_k(const float* __restrict__ in,
                                               __half* __restrict__ out, int n4) {
  int i = blockIdx.x * 256 + threadIdx.x;
  if (i >= n4) return;
  float4 v = *(const float4*)&in[i << 2];
  __half2 a = __floats2half2_rn(v.x, v.y);
  __half2 b = __floats2half2_rn(v.z, v.w);
  uint2 p;
  p.x = *reinterpret_cast<const unsigned int*>(&a);
  p.y = *reinterpret_cast<const unsigned int*>(&b);
  *(uint2*)&out[i << 2] = p;
}

// ---------------- weight block-transpose for l1 f4 GEMV ----------------
// Wt1[cc*256 + c*4 + u] = Worig[row=cc*4+u][c], row = h*128+k (512 rows)
// Worig[row][c] = W1[k*256 + h*64 + c]
__global__ __launch_bounds__(256) void tr_w1_k(const float* __restrict__ W1,
                                               float* __restrict__ Wt1) {
  int o = blockIdx.x * 256 + threadIdx.x;  // 0..32767
  if (o >= 64 * 512) return;
  int cc = o >> 8, rem = o & 255, c = rem >> 2, u = rem & 3;
  int row = cc * 4 + u;
  int h = row >> 7, k = row & 127;
  Wt1[o] = W1[k * 256 + (h << 6) + c];
}

// ---------------- CSR build (bucketed by src slice) ----------------
__global__ void zero_int_k(int* __restrict__ p, int n) {
  int i = blockIdx.x * 256 + threadIdx.x;
  if (i < n) p[i] = 0;
}

__global__ void count_deg2_k(const int* __restrict__ src, const int* __restrict__ dst,
                             int* __restrict__ deg2) {
  int e = blockIdx.x * 256 + threadIdx.x;
  if (e < NE) {
    int b = src[e] / SLICE;
    atomicAdd(&deg2[dst[e] * NB + b], 1);
  }
}

// (a) per-block sums
__global__ __launch_bounds__(1024) void scan_part_k(const int* __restrict__ deg2,
                                                    int* __restrict__ part) {
  __shared__ int ws[16];
  int tid = threadIdx.x, w = tid >> 6;
  int i = blockIdx.x * 1024 + tid;
  int v = (i < NR2) ? deg2[i] : 0;
  int s = wisum64(v);
  if ((tid & 63) == 0) ws[w] = s;
  __syncthreads();
  if (tid == 0) {
    int tot = 0;
#pragma unroll
    for (int u = 0; u < 16; ++u) tot += ws[u];
    part[blockIdx.x] = tot;
  }
}

// (b) scan the 196 partials (one small block)
__global__ void scan_mid_k(int* __restrict__ part, int* __restrict__ rp2) {
  __shared__ int sh[256];
  int tid = threadIdx.x;
  int v = (tid < SCAN_BLOCKS) ? part[tid] : 0;
  sh[tid] = v;
  __syncthreads();
  for (int off = 1; off < 256; off <<= 1) {
    int t = (tid >= off) ? sh[tid - off] : 0;
    __syncthreads();
    sh[tid] += t;
    __syncthreads();
  }
  int incl = sh[tid];
  if (tid < SCAN_BLOCKS) part[tid] = incl - v;  // exclusive
  if (tid == SCAN_BLOCKS - 1) rp2[NR2] = incl;  // total == NE
}

// (c) local scan + block offset -> rp2 / cur2
__global__ __launch_bounds__(1024) void scan_apply_k(const int* __restrict__ deg2,
                                                     const int* __restrict__ part,
                                                     int* __restrict__ rp2,
                                                     int* __restrict__ cur2) {
  __shared__ int ws[16];
  int tid = threadIdx.x, lane = tid & 63, w = tid >> 6;
  int i = blockIdx.x * 1024 + tid;
  int v = (i < NR2) ? deg2[i] : 0;
  int incl = v;
#pragma unroll
  for (int off = 1; off < 64; off <<= 1) {
    int t = __shfl_up(incl, off, 64);
    if (lane >= off) incl += t;
  }
  if (lane == 63) ws[w] = incl;
  __syncthreads();
  if (tid == 0) {
    int run = 0;
#pragma unroll
    for (int u = 0; u < 16; ++u) { int t = ws[u]; ws[u] = run; run += t; }
  }
  __syncthreads();
  int excl = incl - v + ws[w] + part[blockIdx.x];
  if (i < NR2) {
    rp2[i] = excl;
    cur2[i] = excl;
  }
}

__global__ void fill_csr2_k(const int* __restrict__ src, const int* __restrict__ dst,
                            int* __restrict__ cur2, int* __restrict__ csr_src) {
  int e = blockIdx.x * 256 + threadIdx.x;
  if (e < NE) {
    int sv = src[e];
    int b = sv / SLICE;
    int pos = atomicAdd(&cur2[dst[e] * NB + b], 1);
    csr_src[pos] = sv;
  }
}

// ---------------- tiny precomputes ----------------
__global__ void compute_q_k(const float* __restrict__ W, const float* __restrict__ al,
                            const float* __restrict__ ar, float* __restrict__ Q, int KDIM) {
  int idx = blockIdx.x * 256 + threadIdx.x;
  if (idx >= KDIM * 8) return;
  int k = idx >> 3, c = idx & 7;
  int h = c & 3;
  const float* av = (c < 4 ? al : ar) + h * 64;
  const float* wrow = W + (size_t)k * 256 + h * 64;
  float s = 0.0f;
  for (int m = 0; m < 64; ++m) s += wrow[m] * av[m];
  Q[idx] = s;
}

__global__ void compute_m_k(const float* __restrict__ Wh2, const float* __restrict__ Wo,
                            float* __restrict__ M) {
  int row = blockIdx.x;  // 0..255
  int d = threadIdx.x;   // 0..63
  int h = row >> 6, k = row & 63;
  float s = 0.0f;
  for (int j = 0; j < 64; ++j)
    s += Wh2[k * 256 + h * 64 + j] * Wo[(h * 64 + j) * 64 + d];
  M[row * 64 + d] = s;
}

__global__ void compute_c_k(const float* __restrict__ bh2, const float* __restrict__ Wo,
                            const float* __restrict__ bo, float* __restrict__ cvec) {
  int d = threadIdx.x;
  if (d >= 64) return;
  float s = bo[d];
  for (int m = 0; m < 256; ++m) s += bh2[m] * Wo[m * 64 + d];
  cvec[d] = s;
}

// ---------------- el/er for layer 1 (fp32 input, exact) ----------------
__global__ __launch_bounds__(256) void eler_l1_k(const float* __restrict__ X,
                                                 const float* __restrict__ Q,
                                                 float* __restrict__ elp,
                                                 float* __restrict__ erp) {
  int n = RFL(blockIdx.x * 4 + (threadIdx.x >> 6));
  int lane = threadIdx.x & 63;
  float2 xv = *(const float2*)&X[(n << 7) + (lane << 1)];
  float4 qa0 = *(const float4*)&Q[(lane * 2) * 8];
  float4 qb0 = *(const float4*)&Q[(lane * 2) * 8 + 4];
  float4 qa1 = *(const float4*)&Q[(lane * 2 + 1) * 8];
  float4 qb1 = *(const float4*)&Q[(lane * 2 + 1) * 8 + 4];
  float p[8];
  p[0] = xv.x * qa0.x + xv.y * qa1.x; p[1] = xv.x * qa0.y + xv.y * qa1.y;
  p[2] = xv.x * qa0.z + xv.y * qa1.z; p[3] = xv.x * qa0.w + xv.y * qa1.w;
  p[4] = xv.x * qb0.x + xv.y * qb1.x; p[5] = xv.x * qb0.y + xv.y * qb1.y;
  p[6] = xv.x * qb0.z + xv.y * qb1.z; p[7] = xv.x * qb0.w + xv.y * qb1.w;
#pragma unroll
  for (int c = 0; c < 8; ++c) p[c] = wsum64(p[c]);
  if (lane == 0) {
    *(float4*)&elp[n << 2] = make_float4(p[0], p[1], p[2], p[3]);
    *(float4*)&erp[n << 2] = make_float4(p[4], p[5], p[6], p[7]);
  }
}

// ---------------- bucket edge-loop body (64-dim, fp16 x) ----------------
__device__ __forceinline__ void agg_bucket64(const __half* __restrict__ x,
                                             const float* __restrict__ el,
                                             const int* __restrict__ csr,
                                             int beg, int end, int q, int r4,
                                             float erq, float4& a, float& sw) {
  int j = beg;
  for (; j + 4 <= end; j += 4) {
    int s0 = csr[j + 0], s1 = csr[j + 1], s2 = csr[j + 2], s3 = csr[j + 3];
    float e0 = el[(s0 << 2) + q], e1 = el[(s1 << 2) + q];
    float e2 = el[(s2 << 2) + q], e3 = el[(s3 << 2) + q];
    uint2 h0 = *(const uint2*)&x[(s0 << 6) + r4];
    uint2 h1 = *(const uint2*)&x[(s1 << 6) + r4];
    uint2 h2 = *(const uint2*)&x[(s2 << 6) + r4];
    uint2 h3 = *(const uint2*)&x[(s3 << 6) + r4];
    float4 x0 = h4tof4(h0);
    float4 x1 = h4tof4(h1);
    float4 x2 = h4tof4(h2);
    float4 x3 = h4tof4(h3);
    float w0 = __expf(lrelu(e0 + erq)), w1 = __expf(lrelu(e1 + erq));
    float w2 = __expf(lrelu(e2 + erq)), w3 = __expf(lrelu(e3 + erq));
    sw += w0 + w1 + w2 + w3;
    a.x = fmaf(w0, x0.x, a.x); a.y = fmaf(w0, x0.y, a.y);
    a.z = fmaf(w0, x0.z, a.z); a.w = fmaf(w0, x0.w, a.w);
    a.x = fmaf(w1, x1.x, a.x); a.y = fmaf(w1, x1.y, a.y);
    a.z = fmaf(w1, x1.z, a.z); a.w = fmaf(w1, x1.w, a.w);
    a.x = fmaf(w2, x2.x, a.x); a.y = fmaf(w2, x2.y, a.y);
    a.z = fmaf(w2, x2.z, a.z); a.w = fmaf(w2, x2.w, a.w);
    a.x = fmaf(w3, x3.x, a.x); a.y = fmaf(w3, x3.y, a.y);
    a.z = fmaf(w3, x3.z, a.z); a.w = fmaf(w3, x3.w, a.w);
  }
  for (; j < end; ++j) {
    int s0 = csr[j];
    float e0 = el[(s0 << 2) + q];
    uint2 h0 = *(const uint2*)&x[(s0 << 6) + r4];
    float4 x0 = h4tof4(h0);
    float w0 = __expf(lrelu(e0 + erq));
    sw += w0;
    a.x = fmaf(w0, x0.x, a.x); a.y = fmaf(w0, x0.y, a.y);
    a.z = fmaf(w0, x0.z, a.z); a.w = fmaf(w0, x0.w, a.w);
  }
}

// ---------------- fused hidden layer (bucketed fp16 agg + scalar GEMV) ---------
__global__ __launch_bounds__(256) void fused_hidden_k(
    const __half* __restrict__ x, const float* __restrict__ el,
    const float* __restrict__ er, const float* __restrict__ W,
    const float* __restrict__ b, const float* __restrict__ Qn,
    const int* __restrict__ rp2, const int* __restrict__ csr_src,
    __half* __restrict__ hout, float* __restrict__ eln, float* __restrict__ ern) {
  __shared__ float gs[4][1024];
  int wave = threadIdx.x >> 6, lane = threadIdx.x & 63;
  int q = lane >> 4, r = lane & 15, r4 = r << 2;
  int base = (blockIdx.x * 4 + wave) * 4;
  float* gw = gs[wave];
  float4 av[4];
  float swv[4], erqv[4];
#pragma unroll
  for (int t = 0; t < 4; ++t) {
    av[t] = make_float4(0.f, 0.f, 0.f, 0.f);
    swv[t] = 0.f;
    erqv[t] = er[((base + t) << 2) + q];
  }
#pragma unroll 1
  for (int bkt = 0; bkt < NB; ++bkt) {
#pragma unroll
    for (int t = 0; t < 4; ++t) {
      int nb = RFL((base + t) * NB + bkt);
      int beg = rp2[nb], end = rp2[nb + 1];
      agg_bucket64(x, el, csr_src, beg, end, q, r4, erqv[t], av[t], swv[t]);
    }
  }
#pragma unroll
  for (int t = 0; t < 4; ++t) {
    float inv = swv[t] > 0.f ? 1.0f / swv[t] : 0.f;
    *(float4*)&gw[t * 256 + (q << 6) + r4] =
        make_float4(av[t].x * inv, av[t].y * inv, av[t].z * inv, av[t].w * inv);
  }
  float y0 = 0.f, y1 = 0.f, y2 = 0.f, y3 = 0.f;
  for (int rr = 0; rr < 256; rr += 4) {
#pragma unroll
    for (int u = 0; u < 4; ++u) {
      int row = rr + u;
      int h = row >> 6, k = row & 63;
      float sv = W[k * 256 + (h << 6) + lane];
      y0 = fmaf(gw[0 * 256 + row], sv, y0);
      y1 = fmaf(gw[1 * 256 + row], sv, y1);
      y2 = fmaf(gw[2 * 256 + row], sv, y2);
      y3 = fmaf(gw[3 * 256 + row], sv, y3);
    }
  }
  float bsum = b[lane] + b[64 + lane] + b[128 + lane] + b[192 + lane];
  float4 qa = *(const float4*)&Qn[lane * 8];
  float4 qb = *(const float4*)&Qn[lane * 8 + 4];
  float ys[4] = {y0, y1, y2, y3};
#pragma unroll
  for (int t = 0; t < 4; ++t) {
    int n = base + t;
    float yv = 0.25f * (ys[t] + bsum);
    hout[(n << 6) + lane] = __float2half(yv);
    float e0 = wsum64(yv * qa.x), e1 = wsum64(yv * qa.y);
    float e2 = wsum64(yv * qa.z), e3 = wsum64(yv * qa.w);
    float r0 = wsum64(yv * qb.x), r1 = wsum64(yv * qb.y);
    float r2 = wsum64(yv * qb.z), r3 = wsum64(yv * qb.w);
    if (lane == 0) {
      *(float4*)&eln[n << 2] = make_float4(e0, e1, e2, e3);
      *(float4*)&ern[n << 2] = make_float4(r0, r1, r2, r3);
    }
  }
}

// ---------------- fused layer 1: fp16 gather + f4 GEMV (Wt1) ----------------
__global__ __launch_bounds__(256) void fused_l1_k(
    const __half* __restrict__ x, const float* __restrict__ el,
    const float* __restrict__ er, const float* __restrict__ Wt1,
    const float* __restrict__ b, const float* __restrict__ Qn,
    const int* __restrict__ rp2, const int* __restrict__ csr_src,
    __half* __restrict__ hout, float* __restrict__ eln, float* __restrict__ ern) {
  __shared__ float gs[4][2048];
  int wave = threadIdx.x >> 6, lane = threadIdx.x & 63;
  int q = lane >> 4, r = lane & 15, r8 = r << 3;
  int base = (blockIdx.x * 4 + wave) * 4;
  float* gw = gs[wave];
#pragma unroll 1
  for (int t = 0; t < 4; ++t) {
    int n = RFL(base + t);
    int beg = rp2[n * NB], end = rp2[(n + 1) * NB];  // merged bucket range
    float erq = er[(n << 2) + q];
    float4 aA = make_float4(0.f, 0.f, 0.f, 0.f);
    float4 aB = make_float4(0.f, 0.f, 0.f, 0.f);
    float sw = 0.f;
#define ESTEP(elv, ha)                      \
  do {                                      \
    float4 xa, xb;                          \
    h8tof8((ha), xa, xb);                   \
    float w = __expf(lrelu((elv) + erq));   \
    sw += w;                                \
    aA.x = fmaf(w, xa.x, aA.x);             \
    aA.y = fmaf(w, xa.y, aA.y);             \
    aA.z = fmaf(w, xa.z, aA.z);             \
    aA.w = fmaf(w, xa.w, aA.w);             \
    aB.x = fmaf(w, xb.x, aB.x);             \
    aB.y = fmaf(w, xb.y, aB.y);             \
    aB.z = fmaf(w, xb.z, aB.z);             \
    aB.w = fmaf(w, xb.w, aB.w);             \
  } while (0)
    int j = beg;
    for (; j + 8 <= end; j += 8) {
      int s0 = csr_src[j + 0], s1 = csr_src[j + 1];
      int s2 = csr_src[j + 2], s3 = csr_src[j + 3];
      int s4 = csr_src[j + 4], s5 = csr_src[j + 5];
      int s6 = csr_src[j + 6], s7 = csr_src[j + 7];
      float e0 = el[(s0 << 2) + q], e1 = el[(s1 << 2) + q];
      float e2 = el[(s2 << 2) + q], e3 = el[(s3 << 2) + q];
      float e4 = el[(s4 << 2) + q], e5 = el[(s5 << 2) + q];
      float e6 = el[(s6 << 2) + q], e7 = el[(s7 << 2) + q];
      uint4 hA0 = *(const uint4*)&x[(s0 << 7) + r8];
      uint4 hA1 = *(const uint4*)&x[(s1 << 7) + r8];
      uint4 hA2 = *(const uint4*)&x[(s2 << 7) + r8];
      uint4 hA3 = *(const uint4*)&x[(s3 << 7) + r8];
      uint4 hA4 = *(const uint4*)&x[(s4 << 7) + r8];
      uint4 hA5 = *(const uint4*)&x[(s5 << 7) + r8];
      uint4 hA6 = *(const uint4*)&x[(s6 << 7) + r8];
      uint4 hA7 = *(const uint4*)&x[(s7 << 7) + r8];
      ESTEP(e0, hA0); ESTEP(e1, hA1); ESTEP(e2, hA2); ESTEP(e3, hA3);
      ESTEP(e4, hA4); ESTEP(e5, hA5); ESTEP(e6, hA6); ESTEP(e7, hA7);
    }
    for (; j < end; ++j) {
      int s0 = csr_src[j];
      float e0 = el[(s0 << 2) + q];
      uint4 hA0 = *(const uint4*)&x[(s0 << 7) + r8];
      ESTEP(e0, hA0);
    }
#undef ESTEP
    float inv = sw > 0.f ? 1.0f / sw : 0.f;
    *(float4*)&gw[t * 512 + (q << 7) + r8] =
        make_float4(aA.x * inv, aA.y * inv, aA.z * inv, aA.w * inv);
    *(float4*)&gw[t * 512 + (q << 7) + r8 + 4] =
        make_float4(aB.x * inv, aB.y * inv, aB.z * inv, aB.w * inv);
  }
  // f4 GEMV over 512 rows (block-transposed Wt1; coalesced)
  float y0 = 0.f, y1 = 0.f, y2 = 0.f, y3 = 0.f;
  int l4 = lane << 2;
  for (int rr = 0; rr < 512; rr += 4) {
    float4 wv = *(const float4*)&Wt1[(rr << 6) + l4];  // (rr/4)*256 + lane*4
    float4 g0 = *(const float4*)&gw[0 * 512 + rr];
    float4 g1 = *(const float4*)&gw[1 * 512 + rr];
    float4 g2 = *(const float4*)&gw[2 * 512 + rr];
    float4 g3 = *(const float4*)&gw[3 * 512 + rr];
    y0 = fmaf(g0.x, wv.x, y0); y0 = fmaf(g0.y, wv.y, y0);
    y0 = fmaf(g0.z, wv.z, y0); y0 = fmaf(g0.w, wv.w, y0);
    y1 = fmaf(g1.x, wv.x, y1); y1 = fmaf(g1.y, wv.y, y1);
    y1 = fmaf(g1.z, wv.z, y1); y1 = fmaf(g1.w, wv.w, y1);
    y2 = fmaf(g2.x, wv.x, y2); y2 = fmaf(g2.y, wv.y, y2);
    y2 = fmaf(g2.z, wv.z, y2); y2 = fmaf(g2.w, wv.w, y2);
    y3 = fmaf(g3.x, wv.x, y3); y3 = fmaf(g3.y, wv.y, y3);
    y3 = fmaf(g3.z, wv.z, y3); y3 = fmaf(g3.w, wv.w, y3);
  }
  float bsum = b[lane] + b[64 + lane] + b[128 + lane] + b[192 + lane];
  float4 qa = *(const float4*)&Qn[lane * 8];
  float4 qb = *(const float4*)&Qn[lane * 8 + 4];
  float ys[4] = {y0, y1, y2, y3};
#pragma unroll
  for (int t = 0; t < 4; ++t) {
    int n = base + t;
    float yv = 0.25f * (ys[t] + bsum);
    hout[(n << 6) + lane] = __float2half(yv);
    float e0 = wsum64(yv * qa.x), e1 = wsum64(yv * qa.y);
    float e2 = wsum64(yv * qa.z), e3 = wsum64(yv * qa.w);
    float r0 = wsum64(yv * qb.x), r1 = wsum64(yv * qb.y);
    float r2 = wsum64(yv * qb.z), r3 = wsum64(yv * qb.w);
    if (lane == 0) {
      *(float4*)&eln[n << 2] = make_float4(e0, e1, e2, e3);
      *(float4*)&ern[n << 2] = make_float4(r0, r1, r2, r3);
    }
  }
}

// ---------------- fused final (bucketed fp16 agg + scalar GEMV(M) + LN) --------
__global__ __launch_bounds__(256) void fused_final_k(
    const __half* __restrict__ x, const float* __restrict__ el,
    const float* __restrict__ er, const float* __restrict__ M,
    const float* __restrict__ cvec, const int* __restrict__ rp2,
    const int* __restrict__ csr_src, float* __restrict__ out) {
  __shared__ float gs[4][1024];
  int wave = threadIdx.x >> 6, lane = threadIdx.x & 63;
  int q = lane >> 4, r = lane & 15, r4 = r << 2;
  int base = (blockIdx.x * 4 + wave) * 4;
  float* gw = gs[wave];
  float4 av[4];
  float swv[4], erqv[4];
#pragma unroll
  for (int t = 0; t < 4; ++t) {
    av[t] = make_float4(0.f, 0.f, 0.f, 0.f);
    swv[t] = 0.f;
    erqv[t] = er[((base + t) << 2) + q];
  }
#pragma unroll 1
  for (int bkt = 0; bkt < NB; ++bkt) {
#pragma unroll
    for (int t = 0; t < 4; ++t) {
      int nb = RFL((base + t) * NB + bkt);
      int beg = rp2[nb], end = rp2[nb + 1];
      agg_bucket64(x, el, csr_src, beg, end, q, r4, erqv[t], av[t], swv[t]);
    }
  }
#pragma unroll
  for (int t = 0; t < 4; ++t) {
    float inv = swv[t] > 0.f ? 1.0f / swv[t] : 0.f;
    *(float4*)&gw[t * 256 + (q << 6) + r4] =
        make_float4(av[t].x * inv, av[t].y * inv, av[t].z * inv, av[t].w * inv);
  }
  float y0 = 0.f, y1 = 0.f, y2 = 0.f, y3 = 0.f;
  for (int rr = 0; rr < 256; rr += 4) {
#pragma unroll
    for (int u = 0; u < 4; ++u) {
      int row = rr + u;
      float sv = M[(row << 6) + lane];
      y0 = fmaf(gw[0 * 256 + row], sv, y0);
      y1 = fmaf(gw[1 * 256 + row], sv, y1);
      y2 = fmaf(gw[2 * 256 + row], sv, y2);
      y3 = fmaf(gw[3 * 256 + row], sv, y3);
    }
  }
  float cl = cvec[lane];
  float ys[4] = {y0 + cl, y1 + cl, y2 + cl, y3 + cl};
#pragma unroll
  for (int t = 0; t < 4; ++t) {
    int n = base + t;
    float y = ys[t];
    float mu = wsum64(y) * (1.0f / 64.0f);
    float dv = y - mu;
    float var = wsum64(dv * dv) * (1.0f / 64.0f);
    out[(n << 6) + lane] = dv * rsqrtf(var + 1e-5f);
  }
}

// ---------------- launch ----------------
extern "C" void kernel_launch(void* const* d_in, const int* in_sizes, int n_in,
                              void* d_out, int out_size, void* d_ws, size_t ws_size,
                              hipStream_t stream) {
  const float* in_feat = (const float*)d_in[0];
  const int* src = (const int*)d_in[1];
  const int* dst = (const int*)d_in[2];
  const float* W1 = (const float*)d_in[3];
  const float* al1 = (const float*)d_in[4];
  const float* ar1 = (const float*)d_in[5];
  const float* b1 = (const float*)d_in[6];
  const float* Wh = (const float*)d_in[7];   // [3][64][256]
  const float* alh = (const float*)d_in[8];  // [3][4][64]
  const float* arh = (const float*)d_in[9];  // [3][4][64]
  const float* bh = (const float*)d_in[10];  // [3][256]
  const float* Wo = (const float*)d_in[11];  // [256][64]
  const float* bo = (const float*)d_in[12];  // [64]
  float* out = (float*)d_out;

  char* ws = (char*)d_ws;
  size_t off = 0;
  auto alloc = [&](size_t bytes) {
    void* p = ws + off;
    off = (off + bytes + 255) & ~(size_t)255;
    return p;
  };
  __half* x16 = (__half*)alloc((size_t)NN * 128 * 2);
  __half* h_a = (__half*)alloc((size_t)NN * 64 * 2);
  __half* h_b = (__half*)alloc((size_t)NN * 64 * 2);
  float* el_a = (float*)alloc((size_t)NN * 4 * 4);
  float* er_a = (float*)alloc((size_t)NN * 4 * 4);
  float* el_b = (float*)alloc((size_t)NN * 4 * 4);
  float* er_b = (float*)alloc((size_t)NN * 4 * 4);
  float* Q1 = (float*)alloc(128 * 8 * 4);
  float* Q2 = (float*)alloc(64 * 8 * 4);
  float* Q3 = (float*)alloc(64 * 8 * 4);
  float* Q4 = (float*)alloc(64 * 8 * 4);
  float* M = (float*)alloc(256 * 64 * 4);
  float* Wt1 = (float*)alloc(512 * 64 * 4);
  float* cvec = (float*)alloc(64 * 4);
  int* deg2 = (int*)alloc((size_t)NR2 * 4);
  int* rp2 = (int*)alloc((size_t)(NR2 + 1) * 4);
  int* cur2 = (int*)alloc((size_t)NR2 * 4);
  int* part = (int*)alloc((size_t)SCAN_BLOCKS * 4);
  int* csr_src = (int*)alloc((size_t)NE * 4);
  (void)ws_size; (void)in_sizes; (void)n_in; (void)out_size;

  // bucketed CSR build (hierarchical scan)
  zero_int_k<<<(NR2 + 255) / 256, 256, 0, stream>>>(deg2, NR2);
  count_deg2_k<<<(NE + 255) / 256, 256, 0, stream>>>(src, dst, deg2);
  scan_part_k<<<SCAN_BLOCKS, 1024, 0, stream>>>(deg2, part);
  scan_mid_k<<<1, 256, 0, stream>>>(part, rp2);
  scan_apply_k<<<SCAN_BLOCKS, 1024, 0, stream>>>(deg2, part, rp2, cur2);
  fill_csr2_k<<<(NE + 255) / 256, 256, 0, stream>>>(src, dst, cur2, csr_src);

  // in_feat -> fp16
  cvt_x_k<<<(NN * 128 / 4 + 255) / 256, 256, 0, stream>>>(in_feat, x16, NN * 128 / 4);

  // tiny precomputes
  compute_q_k<<<4, 256, 0, stream>>>(W1, al1, ar1, Q1, 128);
  compute_q_k<<<2, 256, 0, stream>>>(Wh + 0 * 64 * 256, alh + 0 * 256, arh + 0 * 256, Q2, 64);
  compute_q_k<<<2, 256, 0, stream>>>(Wh + 1 * 64 * 256, alh + 1 * 256, arh + 1 * 256, Q3, 64);
  compute_q_k<<<2, 256, 0, stream>>>(Wh + 2 * 64 * 256, alh + 2 * 256, arh + 2 * 256, Q4, 64);
  compute_m_k<<<256, 64, 0, stream>>>(Wh + 2 * 64 * 256, Wo, M);
  compute_c_k<<<1, 64, 0, stream>>>(bh + 2 * 256, Wo, bo, cvec);
  tr_w1_k<<<128, 256, 0, stream>>>(W1, Wt1);

  const int FUSED_GRID = NN / 16;  // 3125
  const int ELER_GRID = NN / 4;    // 12500

  // layer 1
  eler_l1_k<<<ELER_GRID, 256, 0, stream>>>(in_feat, Q1, el_a, er_a);
  fused_l1_k<<<FUSED_GRID, 256, 0, stream>>>(x16, el_a, er_a, Wt1, b1, Q2,
                                             rp2, csr_src, h_a, el_b, er_b);
  // hidden layers
  fused_hidden_k<<<FUSED_GRID, 256, 0, stream>>>(h_a, el_b, er_b, Wh + 0 * 64 * 256,
                                                 bh + 0 * 256, Q3, rp2, csr_src,
                                                 h_b, el_a, er_a);
  fused_hidden_k<<<FUSED_GRID, 256, 0, stream>>>(h_b, el_a, er_a, Wh + 1 * 64 * 256,
                                                 bh + 1 * 256, Q4, rp2, csr_src,
                                                 h_a, el_b, er_b);
  // final layer + out_ln + LayerNorm
  fused_final_k<<<FUSED_GRID, 256, 0, stream>>>(h_a, el_b, er_b, M, cvec,
                                                rp2, csr_src, out);
}